// Round 2
// baseline (1860.144 us; speedup 1.0000x reference)
//
#include <hip/hip_runtime.h>
#include <stdint.h>

#define K_DIM 4096
#define N_DIM 16384
#define M_DIM 8192

typedef _Float16 half8 __attribute__((ext_vector_type(8)));
typedef float floatx4 __attribute__((ext_vector_type(4)));

// async 16B global -> LDS (direct DMA, no VGPR round trip)
__device__ inline void gld_lds16(const void* g, void* l) {
  __builtin_amdgcn_global_load_lds(
      (const __attribute__((address_space(1))) void*)g,
      (__attribute__((address_space(3))) void*)l, 16, 0, 0);
}

// ---- pre-pass converters: fp32 -> f16, int32 -> f16 (8 elems/thread) ----
__global__ __launch_bounds__(256) void cvt_f32_f16_k(const float* __restrict__ in,
                                                     _Float16* __restrict__ out) {
  size_t idx = (size_t)blockIdx.x * 256 + threadIdx.x;
  const float4* p = (const float4*)in + idx * 2;
  float4 v0 = p[0], v1 = p[1];
  half8 h;
  h[0] = (_Float16)v0.x; h[1] = (_Float16)v0.y; h[2] = (_Float16)v0.z; h[3] = (_Float16)v0.w;
  h[4] = (_Float16)v1.x; h[5] = (_Float16)v1.y; h[6] = (_Float16)v1.z; h[7] = (_Float16)v1.w;
  *((half8*)out + idx) = h;
}

__global__ __launch_bounds__(256) void cvt_i32_f16_k(const int* __restrict__ in,
                                                     _Float16* __restrict__ out) {
  size_t idx = (size_t)blockIdx.x * 256 + threadIdx.x;
  const int4* p = (const int4*)in + idx * 2;
  int4 v0 = p[0], v1 = p[1];
  half8 h;
  h[0] = (_Float16)v0.x; h[1] = (_Float16)v0.y; h[2] = (_Float16)v0.z; h[3] = (_Float16)v0.w;
  h[4] = (_Float16)v1.x; h[5] = (_Float16)v1.y; h[6] = (_Float16)v1.z; h[7] = (_Float16)v1.w;
  *((half8*)out + idx) = h;
}

// =====================================================================
// 256x256 8-phase GEMM with REGISTER-PIPELINED fragment reads.
// C[m,n] = sum_k A[m,k]*B[n,k].  512 thr = 8 waves (2M x 4N); wave tile
// 128x64 = acc[8][4].  LDS: 2 x (A 256x64 + B 256x64) f16 = 128 KB,
// XOR-swizzled at 16B granules (slot = chunk ^ (row&7)).
//
// Key change vs prior round: ds_reads issued in phase p feed phase p+1's
// MFMAs, so each MFMA cluster depends only on PREVIOUS-phase reads ->
// the LDS pipe drains the new reads UNDER the MFMA cluster (counted
// lgkmcnt inserted by compiler), instead of serializing read->MFMA.
//
// Per K-tile t (2 barriers/phase, sched_barrier-pinned):
//  P1: read b0[0..3](t)          ; stage (t+1).B h0 ; MFMA a0 x b0[0,1]
//  P2: read a1(t), b1[0,1](t)    ; stage (t+1).B h1 ; MFMA a0 x b0[2,3]
//  P3: read b1[2,3](t)           ;                  ; MFMA a1 x b1[0,1]
//      vmcnt(4)  -> retires (t+1).A (issued t-1 P4; ~6 phases slack)
//  P4: read a0(t+1) from buf^1   ; stage (t+2).A    ; MFMA a1 x b1[2,3]
//      vmcnt(4)  -> retires (t+1).B, leaves (t+2).A in flight (never 0)
//
// Hazard audit: reads of region X issued at phase p retire at phase
// p+1's lgkm wait; the stage overwriting X sits >=1 barrier later.
// =====================================================================
__global__ __launch_bounds__(512, 2) void qgemm256_k(
    const _Float16* __restrict__ Ah, const _Float16* __restrict__ Bh,
    const float* __restrict__ scale_p, const float* __restrict__ bias,
    float* __restrict__ out) {
  constexpr int BK = 64;
  constexpr int NT = K_DIM / BK;  // 64 K-tiles
  __shared__ __align__(16) _Float16 sA[2][256 * BK];  // 64 KB
  __shared__ __align__(16) _Float16 sB[2][256 * BK];  // 64 KB

  const int tid  = threadIdx.x;
  const int lane = tid & 63;
  const int wid  = tid >> 6;   // 0..7
  const int wm   = wid >> 2;   // 0..1
  const int wn   = wid & 3;    // 0..3
  const int q    = lane >> 4;  // 0..3
  const int l15  = lane & 15;

  // T1: XCD-aware bijective swizzle (nwg = 2048, divisible by 8)
  const int nbn = N_DIM / 256;                                  // 64
  int lin = blockIdx.y * gridDim.x + blockIdx.x;
  int swz = (lin & 7) * ((M_DIM / 256) * nbn / 8) + (lin >> 3);
  const int bn = swz % nbn;
  const int bm = swz / nbn;

  // staging geometry: half-tile = 128 rows x 64 f16 = 1024 x 16B granules;
  // thread covers granules {tid, tid+512} (rows r0, r0+64, same slot).
  const int s_slot = tid & 7;
  const int r0     = tid >> 3;  // 0..63
  const int cc     = s_slot ^ (r0 & 7);
  const _Float16* Agp = Ah + (size_t)(bm * 256 + r0) * K_DIM + cc * 8;
  const _Float16* Bgp = Bh + (size_t)(bn * 256 + r0) * K_DIM + cc * 8;

#define STAGE_A(b, tt, h)                                                        \
  { const _Float16* s_ = Agp + (size_t)(h) * 128 * K_DIM + (tt) * BK;            \
    gld_lds16(s_, &sA[(b)][(h) * 8192 + tid * 8]);                               \
    gld_lds16(s_ + (size_t)64 * K_DIM, &sA[(b)][(h) * 8192 + 4096 + tid * 8]); }
#define STAGE_B(b, tt, h)                                                        \
  { const _Float16* s_ = Bgp + (size_t)(h) * 128 * K_DIM + (tt) * BK;            \
    gld_lds16(s_, &sB[(b)][(h) * 8192 + tid * 8]);                               \
    gld_lds16(s_ + (size_t)64 * K_DIM, &sB[(b)][(h) * 8192 + 4096 + tid * 8]); }
#define MFMA16(d, a_, b_) d = __builtin_amdgcn_mfma_f32_16x16x32_f16(a_, b_, d, 0, 0, 0)
#define SBAR() __builtin_amdgcn_sched_barrier(0)
#define BARRIER() { SBAR(); __builtin_amdgcn_s_barrier(); SBAR(); }

  // fragment read bases (in halves); physical slot = chunk ^ (row&7)
  const int rbA = (wm * 128 + l15) * BK;
  const int rbB = (wn * 64 + l15) * BK;
  const int xt0 = (q ^ (l15 & 7)) * 8;        // kk=0 chunk q
  const int xt1 = ((q + 4) ^ (l15 & 7)) * 8;  // kk=1 chunk q+4

  floatx4 acc[8][4] = {};
  half8 a0[8], a1[8], b0[4], b1[4];  // loop-carried: a0(t) read at t-1's P4

  // prologue: stage tile0 (A,B) + tile1 A (12 loads/wave); vmcnt(4)
  // retires tile0 (oldest 8), leaves tile1.A in flight; prefetch a0(t0).
  STAGE_A(0, 0, 0); STAGE_A(0, 0, 1);
  STAGE_B(0, 0, 0); STAGE_B(0, 0, 1);
  STAGE_A(1, 1, 0); STAGE_A(1, 1, 1);
  asm volatile("s_waitcnt vmcnt(4)" ::: "memory");
  BARRIER();
#pragma unroll
  for (int i = 0; i < 8; ++i) a0[i] = *(const half8*)&sA[0][rbA + i * 1024 + xt0];

#pragma unroll 1
  for (int t = 0; t < NT; ++t) {
    const int buf = t & 1;
    const _Float16* pa  = sA[buf];
    const _Float16* pb  = sB[buf];
    const _Float16* pan = sA[buf ^ 1];  // next tile's A

    // ---- P1: read b0[0..3]; stage (t+1).B h0; MFMA a0 x b0[0,1]
    b0[0] = *(const half8*)&pb[rbB + xt0];
    b0[1] = *(const half8*)&pb[rbB + 1024 + xt0];
    b0[2] = *(const half8*)&pb[rbB + 2048 + xt0];
    b0[3] = *(const half8*)&pb[rbB + 3072 + xt0];
    if (t < NT - 1) STAGE_B(buf ^ 1, t + 1, 0);
    BARRIER();
    __builtin_amdgcn_s_setprio(1);
#pragma unroll
    for (int i = 0; i < 8; ++i) { MFMA16(acc[i][0], a0[i], b0[0]); MFMA16(acc[i][1], a0[i], b0[1]); }
    __builtin_amdgcn_s_setprio(0);
    BARRIER();

    // ---- P2: read a1 + b1[0,1]; stage (t+1).B h1; MFMA a0 x b0[2,3]
#pragma unroll
    for (int i = 0; i < 8; ++i) a1[i] = *(const half8*)&pa[rbA + i * 1024 + xt1];
    b1[0] = *(const half8*)&pb[rbB + xt1];
    b1[1] = *(const half8*)&pb[rbB + 1024 + xt1];
    if (t < NT - 1) STAGE_B(buf ^ 1, t + 1, 1);
    BARRIER();
    __builtin_amdgcn_s_setprio(1);
#pragma unroll
    for (int i = 0; i < 8; ++i) { MFMA16(acc[i][2], a0[i], b0[2]); MFMA16(acc[i][3], a0[i], b0[3]); }
    __builtin_amdgcn_s_setprio(0);
    BARRIER();

    // ---- P3: read b1[2,3]; MFMA a1 x b1[0,1]; vmcnt(4) retires (t+1).A
    b1[2] = *(const half8*)&pb[rbB + 2048 + xt1];
    b1[3] = *(const half8*)&pb[rbB + 3072 + xt1];
    BARRIER();
    __builtin_amdgcn_s_setprio(1);
#pragma unroll
    for (int i = 0; i < 8; ++i) { MFMA16(acc[i][0], a1[i], b1[0]); MFMA16(acc[i][1], a1[i], b1[1]); }
    __builtin_amdgcn_s_setprio(0);
    asm volatile("s_waitcnt vmcnt(4)" ::: "memory");
    BARRIER();

    // ---- P4: prefetch a0(t+1) from buf^1; stage (t+2).A; MFMA a1 x b1[2,3]
    if (t < NT - 1) {
#pragma unroll
      for (int i = 0; i < 8; ++i) a0[i] = *(const half8*)&pan[rbA + i * 1024 + xt0];
    }
    if (t < NT - 2) { STAGE_A(buf, t + 2, 0); STAGE_A(buf, t + 2, 1); }
    BARRIER();
    __builtin_amdgcn_s_setprio(1);
#pragma unroll
    for (int i = 0; i < 8; ++i) { MFMA16(acc[i][2], a1[i], b1[2]); MFMA16(acc[i][3], a1[i], b1[3]); }
    __builtin_amdgcn_s_setprio(0);
    if (t < NT - 2) { asm volatile("s_waitcnt vmcnt(4)" ::: "memory"); }
    else            { asm volatile("s_waitcnt vmcnt(0)" ::: "memory"); }
    BARRIER();
  }

  // epilogue: out = acc*scale + bias   (C/D: col=lane&15, row=q*4+reg)
  const float s = *scale_p;
  float bv[4];
#pragma unroll
  for (int j = 0; j < 4; ++j) bv[j] = bias[bn * 256 + wn * 64 + j * 16 + l15];
  const int mb = bm * 256 + wm * 128 + q * 4;
  const size_t nb = (size_t)bn * 256 + wn * 64 + l15;
#pragma unroll
  for (int i = 0; i < 8; ++i) {
#pragma unroll
    for (int j = 0; j < 4; ++j) {
      size_t off = (size_t)(mb + i * 16) * N_DIM + nb + j * 16;
      floatx4 c = acc[i][j];
      out[off]             = c[0] * s + bv[j];
      out[off + N_DIM]     = c[1] * s + bv[j];
      out[off + 2 * N_DIM] = c[2] * s + bv[j];
      out[off + 3 * N_DIM] = c[3] * s + bv[j];
    }
  }
#undef STAGE_A
#undef STAGE_B
#undef MFMA16
#undef SBAR
#undef BARRIER
}

// ---- fallback 128x128 kernel (no-workspace path), unchanged ----
template <bool FROM_WS>
__global__ __launch_bounds__(256) void qgemm_k(const void* __restrict__ Av,
                                               const void* __restrict__ Bv,
                                               const float* __restrict__ scale_p,
                                               const float* __restrict__ bias,
                                               float* __restrict__ out) {
  constexpr int BK = 64;
  __shared__ __align__(16) _Float16 sA[128 * BK];
  __shared__ __align__(16) _Float16 sB[128 * BK];

  const int tid  = threadIdx.x;
  const int lane = tid & 63;
  const int wid  = tid >> 6;
  const int wm   = wid >> 1, wn = wid & 1;
  const int q    = lane >> 4;
  const int l15  = lane & 15;
  const int bn   = blockIdx.x, bm = blockIdx.y;

  int gI[4], rI[4], cI[4];
#pragma unroll
  for (int p = 0; p < 4; ++p) {
    int g = p * 256 + tid;
    gI[p] = g;
    rI[p] = g >> 3;
    cI[p] = (g & 7) ^ (rI[p] & 7);
  }

  floatx4 acc[4][4] = {};

  const int arow = wm * 64 + l15;
  const int brow = wn * 64 + l15;

  const _Float16* Ahp = nullptr; const _Float16* Bhp = nullptr;
  const float* Af = nullptr;     const int* Bq = nullptr;
  if constexpr (FROM_WS) { Ahp = (const _Float16*)Av; Bhp = (const _Float16*)Bv; }
  else                   { Af = (const float*)Av;     Bq = (const int*)Bv; }

#pragma unroll 1
  for (int k0 = 0; k0 < K_DIM; k0 += BK) {
    if constexpr (FROM_WS) {
#pragma unroll
      for (int p = 0; p < 4; ++p)
        gld_lds16(Ahp + (size_t)(bm * 128 + rI[p]) * K_DIM + k0 + cI[p] * 8, &sA[gI[p] * 8]);
#pragma unroll
      for (int p = 0; p < 4; ++p)
        gld_lds16(Bhp + (size_t)(bn * 128 + rI[p]) * K_DIM + k0 + cI[p] * 8, &sB[gI[p] * 8]);
    } else {
#pragma unroll
      for (int p = 0; p < 4; ++p) {
        const float4* pa =
            (const float4*)(Af + (size_t)(bm * 128 + rI[p]) * K_DIM + k0 + cI[p] * 8);
        float4 v0 = pa[0], v1 = pa[1];
        half8 h;
        h[0] = (_Float16)v0.x; h[1] = (_Float16)v0.y; h[2] = (_Float16)v0.z; h[3] = (_Float16)v0.w;
        h[4] = (_Float16)v1.x; h[5] = (_Float16)v1.y; h[6] = (_Float16)v1.z; h[7] = (_Float16)v1.w;
        *(half8*)&sA[gI[p] * 8] = h;
      }
#pragma unroll
      for (int p = 0; p < 4; ++p) {
        const int4* pb =
            (const int4*)(Bq + (size_t)(bn * 128 + rI[p]) * K_DIM + k0 + cI[p] * 8);
        int4 v0 = pb[0], v1 = pb[1];
        half8 h;
        h[0] = (_Float16)v0.x; h[1] = (_Float16)v0.y; h[2] = (_Float16)v0.z; h[3] = (_Float16)v0.w;
        h[4] = (_Float16)v1.x; h[5] = (_Float16)v1.y; h[6] = (_Float16)v1.z; h[7] = (_Float16)v1.w;
        *(half8*)&sB[gI[p] * 8] = h;
      }
    }
    __syncthreads();

#pragma unroll
    for (int kk = 0; kk < BK; kk += 32) {
      const int xt = ((((kk >> 3) + q) ^ (lane & 7)) * 8);
      half8 af[4], bf[4];
#pragma unroll
      for (int i = 0; i < 4; ++i) af[i] = *(const half8*)&sA[(arow + i * 16) * BK + xt];
#pragma unroll
      for (int j = 0; j < 4; ++j) bf[j] = *(const half8*)&sB[(brow + j * 16) * BK + xt];
#pragma unroll
      for (int i = 0; i < 4; ++i)
#pragma unroll
        for (int j = 0; j < 4; ++j)
          acc[i][j] = __builtin_amdgcn_mfma_f32_16x16x32_f16(af[i], bf[j], acc[i][j], 0, 0, 0);
    }
    __syncthreads();
  }

  const float s = *scale_p;
  float bv[4];
#pragma unroll
  for (int j = 0; j < 4; ++j) bv[j] = bias[bn * 128 + wn * 64 + j * 16 + l15];
  const int mb = bm * 128 + wm * 64 + q * 4;
  const size_t nb = (size_t)bn * 128 + wn * 64 + l15;
#pragma unroll
  for (int i = 0; i < 4; ++i) {
#pragma unroll
    for (int j = 0; j < 4; ++j) {
      size_t off = (size_t)(mb + i * 16) * N_DIM + nb + j * 16;
      floatx4 c = acc[i][j];
      out[off]             = c[0] * s + bv[j];
      out[off + N_DIM]     = c[1] * s + bv[j];
      out[off + 2 * N_DIM] = c[2] * s + bv[j];
      out[off + 3 * N_DIM] = c[3] * s + bv[j];
    }
  }
}

extern "C" void kernel_launch(void* const* d_in, const int* in_sizes, int n_in,
                              void* d_out, int out_size, void* d_ws, size_t ws_size,
                              hipStream_t stream) {
  const float* x     = (const float*)d_in[0];
  const int*   qw    = (const int*)d_in[1];
  const float* scale = (const float*)d_in[2];
  const float* bias  = (const float*)d_in[3];
  float* out = (float*)d_out;

  const size_t xs  = (size_t)M_DIM * K_DIM;
  const size_t wsz = (size_t)N_DIM * K_DIM;
  const size_t need = (xs + wsz) * sizeof(_Float16);  // 201 MB

  if (ws_size >= need) {
    _Float16* xh = (_Float16*)d_ws;
    _Float16* wh = xh + xs;
    cvt_f32_f16_k<<<(int)(xs / 8 / 256), 256, 0, stream>>>(x, xh);
    cvt_i32_f16_k<<<(int)(wsz / 8 / 256), 256, 0, stream>>>(qw, wh);
    dim3 grid(N_DIM / 256, M_DIM / 256);  // 64 x 32 = 2048 blocks
    qgemm256_k<<<grid, 512, 0, stream>>>(xh, wh, scale, bias, out);
  } else {
    dim3 grid(N_DIM / 128, M_DIM / 128);
    qgemm_k<false><<<grid, 256, 0, stream>>>(x, qw, scale, bias, out);
  }
}

// Round 3
// 1786.785 us; speedup vs baseline: 1.0411x; 1.0411x over previous
//
#include <hip/hip_runtime.h>
#include <stdint.h>

#define K_DIM 4096
#define N_DIM 16384
#define M_DIM 8192

typedef _Float16 half8 __attribute__((ext_vector_type(8)));
typedef float floatx4 __attribute__((ext_vector_type(4)));

// async 16B global -> LDS (direct DMA, no VGPR round trip)
__device__ inline void gld_lds16(const void* g, void* l) {
  __builtin_amdgcn_global_load_lds(
      (const __attribute__((address_space(1))) void*)g,
      (__attribute__((address_space(3))) void*)l, 16, 0, 0);
}

// ---- pre-pass converters: fp32 -> f16, int32 -> f16 (8 elems/thread) ----
__global__ __launch_bounds__(256) void cvt_f32_f16_k(const float* __restrict__ in,
                                                     _Float16* __restrict__ out) {
  size_t idx = (size_t)blockIdx.x * 256 + threadIdx.x;
  const float4* p = (const float4*)in + idx * 2;
  float4 v0 = p[0], v1 = p[1];
  half8 h;
  h[0] = (_Float16)v0.x; h[1] = (_Float16)v0.y; h[2] = (_Float16)v0.z; h[3] = (_Float16)v0.w;
  h[4] = (_Float16)v1.x; h[5] = (_Float16)v1.y; h[6] = (_Float16)v1.z; h[7] = (_Float16)v1.w;
  *((half8*)out + idx) = h;
}

__global__ __launch_bounds__(256) void cvt_i32_f16_k(const int* __restrict__ in,
                                                     _Float16* __restrict__ out) {
  size_t idx = (size_t)blockIdx.x * 256 + threadIdx.x;
  const int4* p = (const int4*)in + idx * 2;
  int4 v0 = p[0], v1 = p[1];
  half8 h;
  h[0] = (_Float16)v0.x; h[1] = (_Float16)v0.y; h[2] = (_Float16)v0.z; h[3] = (_Float16)v0.w;
  h[4] = (_Float16)v1.x; h[5] = (_Float16)v1.y; h[6] = (_Float16)v1.z; h[7] = (_Float16)v1.w;
  *((half8*)out + idx) = h;
}

// =====================================================================
// 256x256 GEMM, m201-depth staging: 8 phases per K-TILE-PAIR, one
// half-tile staged per phase, vmcnt(6) only at phases 4 and 8
// (3 half-tiles in flight; every half-tile has >=3 phases of slack
// before its retirement point -> HBM latency fully covered).
//
// Iteration i computes tiles t0=2i (buf0, phases 1-4) and t0+1 (buf1,
// phases 5-8).  Stage slots:
//   P1: (t0+1).A.h1 -> buf1     P5: (t0+2).A.h1 -> buf0
//   P2: (t0+2).B.h0 -> buf0     P6: (t0+3).B.h0 -> buf1
//   P3: (t0+2).B.h1 -> buf0     P7: (t0+3).B.h1 -> buf1
//   P4: (t0+2).A.h0 -> buf0     P8: (t0+3).A.h0 -> buf1
//   vmcnt(6)@P4 retires ...through P1 => tile t0+1 complete.
//   vmcnt(6)@P8 retires ...through P5 => tile t0+2 complete.
//
// WAR invariant: each phase drains its own ds_reads (lgkmcnt(0)) before
// its MFMAs, so by the phase-end barrier all reads of that phase are
// retired; every stage targets a region whose last reader drained >=1
// barrier earlier (B read fully in P1, staged P2/P3; A read by P3,
// staged P4/P5).
//
// Read schedule per tile (deadlines from overwrite slots):
//   P1: b0[0..3], b1[0..3], a0[0..3]  (12 reads, lgkm(8) hint)
//   P2: a0[4..7], a1[0..3]            (8)
//   P3: a1[4..7]                      (4)
//   P4: none
// MFMA (16 per phase, same-phase operands only):
//   P1: acc[0..3][j]  += a0[0..3] x b0[j]
//   P2: acc[4..7][j]  += a0[4..7] x b0[j]
//   P3: acc[0..3][j]  += a1[0..3] x b1[j]
//   P4: acc[4..7][j]  += a1[4..7] x b1[j]
// =====================================================================
__global__ __launch_bounds__(512, 2) void qgemm256_k(
    const _Float16* __restrict__ Ah, const _Float16* __restrict__ Bh,
    const float* __restrict__ scale_p, const float* __restrict__ bias,
    float* __restrict__ out) {
  constexpr int BK = 64;
  constexpr int NT = K_DIM / BK;  // 64 K-tiles
  constexpr int NI = NT / 2;      // 32 pair-iterations
  __shared__ __align__(16) _Float16 sA[2][256 * BK];  // 64 KB
  __shared__ __align__(16) _Float16 sB[2][256 * BK];  // 64 KB

  const int tid  = threadIdx.x;
  const int lane = tid & 63;
  const int wid  = tid >> 6;   // 0..7
  const int wm   = wid >> 2;   // 0..1
  const int wn   = wid & 3;    // 0..3
  const int q    = lane >> 4;  // 0..3
  const int l15  = lane & 15;

  // T1: XCD-aware bijective swizzle (nwg = 2048, divisible by 8)
  const int nbn = N_DIM / 256;  // 64
  int lin = blockIdx.y * gridDim.x + blockIdx.x;
  int swz = (lin & 7) * ((M_DIM / 256) * nbn / 8) + (lin >> 3);
  const int bn = swz % nbn;
  const int bm = swz / nbn;

  // staging geometry: half-tile = 128 rows x 64 f16 = 1024 x 16B granules;
  // thread covers granules {tid, tid+512} (rows r0, r0+64, same slot).
  const int s_slot = tid & 7;
  const int r0     = tid >> 3;  // 0..63
  const int cc     = s_slot ^ (r0 & 7);
  const _Float16* Agp = Ah + (size_t)(bm * 256 + r0) * K_DIM + cc * 8;
  const _Float16* Bgp = Bh + (size_t)(bn * 256 + r0) * K_DIM + cc * 8;

#define STAGE_A(b, tt, h)                                                        \
  { const _Float16* s_ = Agp + (size_t)(h) * 128 * K_DIM + (tt) * BK;            \
    gld_lds16(s_, &sA[(b)][(h) * 8192 + tid * 8]);                               \
    gld_lds16(s_ + (size_t)64 * K_DIM, &sA[(b)][(h) * 8192 + 4096 + tid * 8]); }
#define STAGE_B(b, tt, h)                                                        \
  { const _Float16* s_ = Bgp + (size_t)(h) * 128 * K_DIM + (tt) * BK;            \
    gld_lds16(s_, &sB[(b)][(h) * 8192 + tid * 8]);                               \
    gld_lds16(s_ + (size_t)64 * K_DIM, &sB[(b)][(h) * 8192 + 4096 + tid * 8]); }
#define MFMA_Q(i0, AARR, BARR)                                                   \
  { _Pragma("unroll") for (int ii = 0; ii < 4; ++ii)                             \
    _Pragma("unroll") for (int jj = 0; jj < 4; ++jj)                             \
      acc[(i0) + ii][jj] = __builtin_amdgcn_mfma_f32_16x16x32_f16(               \
          AARR[(i0) + ii], BARR[jj], acc[(i0) + ii][jj], 0, 0, 0); }
#define RD_B4(arr, PB, XT)                                                       \
  { _Pragma("unroll") for (int jj = 0; jj < 4; ++jj)                             \
      arr[jj] = *(const half8*)&PB[rbB + jj * 1024 + (XT)]; }
#define RD_A4(arr, i0, PA, XT)                                                   \
  { _Pragma("unroll") for (int ii = 0; ii < 4; ++ii)                             \
      arr[(i0) + ii] = *(const half8*)&PA[rbA + ((i0) + ii) * 1024 + (XT)]; }
#define LGKM0()                                                                  \
  { asm volatile("s_waitcnt lgkmcnt(0)" ::: "memory");                           \
    __builtin_amdgcn_sched_barrier(0); }
#define PRIO_MFMA(i0, AARR, BARR)                                                \
  { __builtin_amdgcn_s_setprio(1); MFMA_Q(i0, AARR, BARR);                       \
    __builtin_amdgcn_s_setprio(0); }

  // fragment read bases (in halves); physical slot = chunk ^ (row&7)
  const int rbA = (wm * 128 + l15) * BK;
  const int rbB = (wn * 64 + l15) * BK;
  const int xt0 = (q ^ (l15 & 7)) * 8;        // kk=0 chunk q
  const int xt1 = ((q + 4) ^ (l15 & 7)) * 8;  // kk=1 chunk q+4

  floatx4 acc[8][4] = {};

  // prologue: tile0 all 4 halves (8 loads), then tile1 {B0,B1,A0} (6).
  // vmcnt(6) retires the 8 oldest = tile0 complete; 6 stay in flight.
  STAGE_A(0, 0, 0); STAGE_A(0, 0, 1);
  STAGE_B(0, 0, 0); STAGE_B(0, 0, 1);
  STAGE_B(1, 1, 0); STAGE_B(1, 1, 1);
  STAGE_A(1, 1, 0);
  asm volatile("s_waitcnt vmcnt(6)" ::: "memory");
  __builtin_amdgcn_s_barrier();

#pragma unroll 1
  for (int i = 0; i < NI; ++i) {
    const int t0 = 2 * i;
    const bool more = (i < NI - 1);
    half8 a0[8], a1[8], b0[4], b1[4];

    // ================= tile t0 from buf0 =================
    {
      const _Float16* pa = sA[0];
      const _Float16* pb = sB[0];
      // ---- P1
      RD_B4(b0, pb, xt0);
      RD_B4(b1, pb, xt1);
      RD_A4(a0, 0, pa, xt0);
      STAGE_A(1, t0 + 1, 1);
      asm volatile("s_waitcnt lgkmcnt(8)" ::: "memory");
      __builtin_amdgcn_s_barrier();
      LGKM0();
      PRIO_MFMA(0, a0, b0);
      __builtin_amdgcn_s_barrier();
      // ---- P2
      RD_A4(a0, 4, pa, xt0);
      RD_A4(a1, 0, pa, xt1);
      if (more) STAGE_B(0, t0 + 2, 0);
      __builtin_amdgcn_s_barrier();
      LGKM0();
      PRIO_MFMA(4, a0, b0);
      __builtin_amdgcn_s_barrier();
      // ---- P3
      RD_A4(a1, 4, pa, xt1);
      if (more) STAGE_B(0, t0 + 2, 1);
      __builtin_amdgcn_s_barrier();
      LGKM0();
      PRIO_MFMA(0, a1, b1);
      __builtin_amdgcn_s_barrier();
      // ---- P4 (no reads)
      if (more) STAGE_A(0, t0 + 2, 0);
      __builtin_amdgcn_s_barrier();
      PRIO_MFMA(4, a1, b1);
      if (more) { asm volatile("s_waitcnt vmcnt(6)" ::: "memory"); }
      else      { asm volatile("s_waitcnt vmcnt(0)" ::: "memory"); }
      __builtin_amdgcn_s_barrier();
    }

    // ================= tile t0+1 from buf1 =================
    {
      const _Float16* pa = sA[1];
      const _Float16* pb = sB[1];
      // ---- P5
      RD_B4(b0, pb, xt0);
      RD_B4(b1, pb, xt1);
      RD_A4(a0, 0, pa, xt0);
      if (more) STAGE_A(0, t0 + 2, 1);
      asm volatile("s_waitcnt lgkmcnt(8)" ::: "memory");
      __builtin_amdgcn_s_barrier();
      LGKM0();
      PRIO_MFMA(0, a0, b0);
      __builtin_amdgcn_s_barrier();
      // ---- P6
      RD_A4(a0, 4, pa, xt0);
      RD_A4(a1, 0, pa, xt1);
      if (more) STAGE_B(1, t0 + 3, 0);
      __builtin_amdgcn_s_barrier();
      LGKM0();
      PRIO_MFMA(4, a0, b0);
      __builtin_amdgcn_s_barrier();
      // ---- P7
      RD_A4(a1, 4, pa, xt1);
      if (more) STAGE_B(1, t0 + 3, 1);
      __builtin_amdgcn_s_barrier();
      LGKM0();
      PRIO_MFMA(0, a1, b1);
      __builtin_amdgcn_s_barrier();
      // ---- P8 (no reads)
      if (more) STAGE_A(1, t0 + 3, 0);
      __builtin_amdgcn_s_barrier();
      PRIO_MFMA(4, a1, b1);
      if (more) { asm volatile("s_waitcnt vmcnt(6)" ::: "memory"); }
      else      { asm volatile("s_waitcnt vmcnt(0)" ::: "memory"); }
      __builtin_amdgcn_s_barrier();
    }
  }

  // epilogue: out = acc*scale + bias   (C/D: col=lane&15, row=q*4+reg)
  const float s = *scale_p;
  float bv[4];
#pragma unroll
  for (int j = 0; j < 4; ++j) bv[j] = bias[bn * 256 + wn * 64 + j * 16 + l15];
  const int mb = bm * 256 + wm * 128 + q * 4;
  const size_t nb = (size_t)bn * 256 + wn * 64 + l15;
#pragma unroll
  for (int i = 0; i < 8; ++i) {
#pragma unroll
    for (int j = 0; j < 4; ++j) {
      size_t off = (size_t)(mb + i * 16) * N_DIM + nb + j * 16;
      floatx4 c = acc[i][j];
      out[off]             = c[0] * s + bv[j];
      out[off + N_DIM]     = c[1] * s + bv[j];
      out[off + 2 * N_DIM] = c[2] * s + bv[j];
      out[off + 3 * N_DIM] = c[3] * s + bv[j];
    }
  }
#undef STAGE_A
#undef STAGE_B
#undef MFMA_Q
#undef RD_B4
#undef RD_A4
#undef LGKM0
#undef PRIO_MFMA
}

// ---- fallback 128x128 kernel (no-workspace path), unchanged ----
template <bool FROM_WS>
__global__ __launch_bounds__(256) void qgemm_k(const void* __restrict__ Av,
                                               const void* __restrict__ Bv,
                                               const float* __restrict__ scale_p,
                                               const float* __restrict__ bias,
                                               float* __restrict__ out) {
  constexpr int BK = 64;
  __shared__ __align__(16) _Float16 sA[128 * BK];
  __shared__ __align__(16) _Float16 sB[128 * BK];

  const int tid  = threadIdx.x;
  const int lane = tid & 63;
  const int wid  = tid >> 6;
  const int wm   = wid >> 1, wn = wid & 1;
  const int q    = lane >> 4;
  const int l15  = lane & 15;
  const int bn   = blockIdx.x, bm = blockIdx.y;

  int gI[4], rI[4], cI[4];
#pragma unroll
  for (int p = 0; p < 4; ++p) {
    int g = p * 256 + tid;
    gI[p] = g;
    rI[p] = g >> 3;
    cI[p] = (g & 7) ^ (rI[p] & 7);
  }

  floatx4 acc[4][4] = {};

  const int arow = wm * 64 + l15;
  const int brow = wn * 64 + l15;

  const _Float16* Ahp = nullptr; const _Float16* Bhp = nullptr;
  const float* Af = nullptr;     const int* Bq = nullptr;
  if constexpr (FROM_WS) { Ahp = (const _Float16*)Av; Bhp = (const _Float16*)Bv; }
  else                   { Af = (const float*)Av;     Bq = (const int*)Bv; }

#pragma unroll 1
  for (int k0 = 0; k0 < K_DIM; k0 += BK) {
    if constexpr (FROM_WS) {
#pragma unroll
      for (int p = 0; p < 4; ++p)
        gld_lds16(Ahp + (size_t)(bm * 128 + rI[p]) * K_DIM + k0 + cI[p] * 8, &sA[gI[p] * 8]);
#pragma unroll
      for (int p = 0; p < 4; ++p)
        gld_lds16(Bhp + (size_t)(bn * 128 + rI[p]) * K_DIM + k0 + cI[p] * 8, &sB[gI[p] * 8]);
    } else {
#pragma unroll
      for (int p = 0; p < 4; ++p) {
        const float4* pa =
            (const float4*)(Af + (size_t)(bm * 128 + rI[p]) * K_DIM + k0 + cI[p] * 8);
        float4 v0 = pa[0], v1 = pa[1];
        half8 h;
        h[0] = (_Float16)v0.x; h[1] = (_Float16)v0.y; h[2] = (_Float16)v0.z; h[3] = (_Float16)v0.w;
        h[4] = (_Float16)v1.x; h[5] = (_Float16)v1.y; h[6] = (_Float16)v1.z; h[7] = (_Float16)v1.w;
        *(half8*)&sA[gI[p] * 8] = h;
      }
#pragma unroll
      for (int p = 0; p < 4; ++p) {
        const int4* pb =
            (const int4*)(Bq + (size_t)(bn * 128 + rI[p]) * K_DIM + k0 + cI[p] * 8);
        int4 v0 = pb[0], v1 = pb[1];
        half8 h;
        h[0] = (_Float16)v0.x; h[1] = (_Float16)v0.y; h[2] = (_Float16)v0.z; h[3] = (_Float16)v0.w;
        h[4] = (_Float16)v1.x; h[5] = (_Float16)v1.y; h[6] = (_Float16)v1.z; h[7] = (_Float16)v1.w;
        *(half8*)&sB[gI[p] * 8] = h;
      }
    }
    __syncthreads();

#pragma unroll
    for (int kk = 0; kk < BK; kk += 32) {
      const int xt = ((((kk >> 3) + q) ^ (lane & 7)) * 8);
      half8 af[4], bf[4];
#pragma unroll
      for (int i = 0; i < 4; ++i) af[i] = *(const half8*)&sA[(arow + i * 16) * BK + xt];
#pragma unroll
      for (int j = 0; j < 4; ++j) bf[j] = *(const half8*)&sB[(brow + j * 16) * BK + xt];
#pragma unroll
      for (int i = 0; i < 4; ++i)
#pragma unroll
        for (int j = 0; j < 4; ++j)
          acc[i][j] = __builtin_amdgcn_mfma_f32_16x16x32_f16(af[i], bf[j], acc[i][j], 0, 0, 0);
    }
    __syncthreads();
  }

  const float s = *scale_p;
  float bv[4];
#pragma unroll
  for (int j = 0; j < 4; ++j) bv[j] = bias[bn * 128 + wn * 64 + j * 16 + l15];
  const int mb = bm * 128 + wm * 64 + q * 4;
  const size_t nb = (size_t)bn * 128 + wn * 64 + l15;
#pragma unroll
  for (int i = 0; i < 4; ++i) {
#pragma unroll
    for (int j = 0; j < 4; ++j) {
      size_t off = (size_t)(mb + i * 16) * N_DIM + nb + j * 16;
      floatx4 c = acc[i][j];
      out[off]             = c[0] * s + bv[j];
      out[off + N_DIM]     = c[1] * s + bv[j];
      out[off + 2 * N_DIM] = c[2] * s + bv[j];
      out[off + 3 * N_DIM] = c[3] * s + bv[j];
    }
  }
}

extern "C" void kernel_launch(void* const* d_in, const int* in_sizes, int n_in,
                              void* d_out, int out_size, void* d_ws, size_t ws_size,
                              hipStream_t stream) {
  const float* x     = (const float*)d_in[0];
  const int*   qw    = (const int*)d_in[1];
  const float* scale = (const float*)d_in[2];
  const float* bias  = (const float*)d_in[3];
  float* out = (float*)d_out;

  const size_t xs  = (size_t)M_DIM * K_DIM;
  const size_t wsz = (size_t)N_DIM * K_DIM;
  const size_t need = (xs + wsz) * sizeof(_Float16);  // 201 MB

  if (ws_size >= need) {
    _Float16* xh = (_Float16*)d_ws;
    _Float16* wh = xh + xs;
    cvt_f32_f16_k<<<(int)(xs / 8 / 256), 256, 0, stream>>>(x, xh);
    cvt_i32_f16_k<<<(int)(wsz / 8 / 256), 256, 0, stream>>>(qw, wh);
    dim3 grid(N_DIM / 256, M_DIM / 256);  // 64 x 32 = 2048 blocks
    qgemm256_k<<<grid, 512, 0, stream>>>(xh, wh, scale, bias, out);
  } else {
    dim3 grid(N_DIM / 128, M_DIM / 128);
    qgemm_k<false><<<grid, 256, 0, stream>>>(x, qw, scale, bias, out);
  }
}